// Round 10
// baseline (1412.992 us; speedup 1.0000x reference)
//
#include <hip/hip_runtime.h>

#define T_TOK 1024
#define D_HID 2048
#define NEXP 32
#define I_EXP 1408
#define TOPK 6
#define NGRP 8
#define GSIZE 4
#define TOPG 3
#define SHI 2816
#define RSCALE 2.5f

typedef __attribute__((ext_vector_type(8))) short short8;
typedef __attribute__((ext_vector_type(4))) float floatx4;

__device__ __forceinline__ unsigned short f2b(float f) {
  unsigned int u = __float_as_uint(f);
  u += 0x7fffu + ((u >> 16) & 1u);   // RNE
  return (unsigned short)(u >> 16);
}

__device__ __forceinline__ float b2f(unsigned short s) {
  return __uint_as_float((unsigned)s << 16);
}

__device__ __forceinline__ short8 pack8s(const float* v) {
  union { uint4 u; short8 s; } o;
  o.u.x = (unsigned)f2b(v[0]) | ((unsigned)f2b(v[1]) << 16);
  o.u.y = (unsigned)f2b(v[2]) | ((unsigned)f2b(v[3]) << 16);
  o.u.z = (unsigned)f2b(v[4]) | ((unsigned)f2b(v[5]) << 16);
  o.u.w = (unsigned)f2b(v[6]) | ((unsigned)f2b(v[7]) << 16);
  return o.s;
}

// ---------------- routing: one block (1 wave) per token ----------------
__global__ __launch_bounds__(64) void k_route(
    const float* __restrict__ x, const float* __restrict__ gw,
    const float* __restrict__ bias, int* __restrict__ tki, float* __restrict__ tkw)
{
  int t = blockIdx.x;
  __shared__ float xs[D_HID];
  __shared__ float sc[NEXP], cor[NEXP];
  int lane = threadIdx.x;
  for (int d = lane * 4; d < D_HID; d += 64 * 4)
    *(float4*)(xs + d) = *(const float4*)(x + (size_t)t * D_HID + d);
  __syncthreads();
  if (lane < NEXP) {
    float acc = 0.f;
    for (int d = 0; d < D_HID; ++d) acc += xs[d] * gw[d * NEXP + lane];
    float s = 1.f / (1.f + expf(-acc));
    sc[lane] = s;
    cor[lane] = s + bias[lane];
  }
  __syncthreads();
  if (lane == 0) {
    float gs[NGRP];
    for (int g = 0; g < NGRP; ++g) {
      float m1 = -INFINITY, m2 = -INFINITY;
      for (int j = 0; j < GSIZE; ++j) {
        float v = cor[g * GSIZE + j];
        if (v > m1) { m2 = m1; m1 = v; } else if (v > m2) m2 = v;
      }
      gs[g] = m1 + m2;
    }
    unsigned gmask = 0;
    for (int rr = 0; rr < TOPG; ++rr) {
      int bi = -1; float bv = -INFINITY;
      for (int g = 0; g < NGRP; ++g)
        if (!((gmask >> g) & 1) && gs[g] > bv) { bv = gs[g]; bi = g; }
      gmask |= 1u << bi;
    }
    unsigned used = 0;
    float wsum = 0.f;
    int idxs[TOPK]; float wsel[TOPK];
    for (int rr = 0; rr < TOPK; ++rr) {
      int bi = -1; float bv = -INFINITY;
      for (int e = 0; e < NEXP; ++e) {
        if (!((gmask >> (e / GSIZE)) & 1)) continue;
        if ((used >> e) & 1) continue;
        if (cor[e] > bv) { bv = cor[e]; bi = e; }
      }
      used |= 1u << bi;
      idxs[rr] = bi; wsel[rr] = sc[bi]; wsum += sc[bi];
    }
    float inv = 1.f / (wsum + 1e-20f);
    for (int rr = 0; rr < TOPK; ++rr) {
      tki[t * TOPK + rr] = idxs[rr];
      tkw[t * TOPK + rr] = wsel[rr] * inv;
    }
  }
}

// ---------------- counts + offsets + padded offsets ----------------
__global__ __launch_bounds__(256) void k_count(const int* __restrict__ tki,
                                               int* __restrict__ cnt, int* __restrict__ offp,
                                               int* __restrict__ poff)
{
  __shared__ int c[NEXP];
  if (threadIdx.x < NEXP) c[threadIdx.x] = 0;
  __syncthreads();
  for (int i = threadIdx.x; i < T_TOK * TOPK; i += 256) atomicAdd(&c[tki[i]], 1);
  __syncthreads();
  if (threadIdx.x == 0) {
    int s = 0, p = 0;
    for (int e = 0; e < NEXP; ++e) {
      offp[e] = s; cnt[e] = c[e]; poff[e] = p;
      s += c[e];
      p += 256 * ((c[e] + 255) / 256);
    }
    offp[NEXP] = s; poff[NEXP] = p;
  }
}

// ---------------- deterministic compaction: one wave per expert ----------------
__global__ __launch_bounds__(64) void k_compact(
    const int* __restrict__ tki, const float* __restrict__ tkw,
    const int* __restrict__ offp, int* __restrict__ tok, float* __restrict__ wts)
{
  int e = blockIdx.x, lane = threadIdx.x;
  int base = offp[e];
  for (int t0 = 0; t0 < T_TOK; t0 += 64) {
    int t = t0 + lane;
    int found = -1;
    for (int j = 0; j < TOPK; ++j)
      if (tki[t * TOPK + j] == e) found = j;
    unsigned long long m = __ballot(found >= 0);
    if (found >= 0) {
      int pos = base + __popcll(m & ((1ull << lane) - 1ull));
      tok[pos] = t;
      wts[pos] = tkw[t * TOPK + found];
    }
    base += __popcll(m);
  }
}

// ---------------- tile-linear A prep (gather + fp32->bf16 cast) ----------------
// Per 256-row chunk: [kt][granule g = koff*256 + m] of 16B (8 bf16 along k).
__global__ __launch_bounds__(256) void k_prep(
    const float* __restrict__ x,
    const int* __restrict__ offp, const int* __restrict__ cnt,
    const int* __restrict__ poff, const int* __restrict__ tok,
    unsigned short* __restrict__ Ap, unsigned short* __restrict__ ApS)
{
  const int ey = blockIdx.x, ch = blockIdx.y, m = threadIdx.x;
  const int* tk = nullptr;
  int nr;
  unsigned short* dst;
  if (ey < NEXP) {
    nr = cnt[ey];
    int pad = poff[ey + 1] - poff[ey];
    if (ch * 256 >= pad) return;
    dst = Ap + ((size_t)(poff[ey] >> 8) + ch) * 64 * 8192;
    tk = tok + offp[ey];
  } else {
    nr = T_TOK;
    dst = ApS + (size_t)ch * 64 * 8192;
  }
  int grow = ch * 256 + m;
  const float* src = nullptr;
  if (grow < nr) {
    int t = tk ? tk[grow] : grow;
    src = x + (size_t)t * D_HID;
  }
  for (int kt = 0; kt < 64; ++kt) {
    #pragma unroll
    for (int ko = 0; ko < 4; ++ko) {
      uint4 w = {0u, 0u, 0u, 0u};
      if (src) {
        const float* s = src + kt * 32 + ko * 8;
        float4 a = *(const float4*)s;
        float4 b = *(const float4*)(s + 4);
        w.x = (unsigned)f2b(a.x) | ((unsigned)f2b(a.y) << 16);
        w.y = (unsigned)f2b(a.z) | ((unsigned)f2b(a.w) << 16);
        w.z = (unsigned)f2b(b.x) | ((unsigned)f2b(b.y) << 16);
        w.w = (unsigned)f2b(b.z) | ((unsigned)f2b(b.w) << 16);
      }
      *(uint4*)(dst + (size_t)kt * 8192 + (ko * 256 + m) * 8) = w;
    }
  }
}

// =================================================================
// Barrier-free register-streaming GEMM.  256 thr = 4 waves M-stacked.
// Wave tile 64m x 32n (acc 4mf x 2nf).  NO LDS, NO barriers.
// A: tile-linear (prep'd) -> per-instr 4x256B contiguous runs (8 lines).
// B: fp32 weights, per-thread k-run scalar dwords, 64 lanes cover 4 rows
//    x 64B (4 lines/instr); f2b-packed to MFMA frag in-register.
// Latency hidden by wave TLP (no LDS -> ~16 waves/CU at ~90 VGPR).
// =================================================================

template<int NKT, int N, bool FUSE>
__device__ __forceinline__ void gu_body(
    const unsigned short* __restrict__ Abase,   // chunk stride NKT*8192 ushorts
    const float* __restrict__ B,
    unsigned short* __restrict__ Gt,            // preact, tile-linear (nktH)
    unsigned short* __restrict__ Ht,            // h out, tile-linear (nktH)
    int nktH, int nch, int nrows, int n0)
{
  const int tid = threadIdx.x;
  const int w = tid >> 6, lane = tid & 63;
  const int c = lane & 15, r = lane >> 4;
  const float* bp0 = B + (size_t)(r * 8) * N + n0 + c;
  const float* bp1 = bp0 + 16;

  for (int ch = 0; ch < nch; ++ch) {
    const unsigned short* Ach = Abase + (size_t)ch * NKT * 8192;
    floatx4 acc[4][2] = {};

    #pragma unroll 1
    for (int kt = 0; kt < NKT; ++kt) {
      float b0[8], b1[8];
      #pragma unroll
      for (int j = 0; j < 8; ++j) b0[j] = bp0[(size_t)(kt * 32 + j) * N];
      #pragma unroll
      for (int j = 0; j < 8; ++j) b1[j] = bp1[(size_t)(kt * 32 + j) * N];
      short8 af[4];
      #pragma unroll
      for (int mf = 0; mf < 4; ++mf)
        af[mf] = *(const short8*)(Ach + ((size_t)kt * 1024 + r * 256 + w * 64 + mf * 16 + c) * 8);
      short8 f0 = pack8s(b0), f1 = pack8s(b1);
      #pragma unroll
      for (int mf = 0; mf < 4; ++mf) {
        acc[mf][0] = __builtin_amdgcn_mfma_f32_16x16x32_bf16(af[mf], f0, acc[mf][0], 0, 0, 0);
        acc[mf][1] = __builtin_amdgcn_mfma_f32_16x16x32_bf16(af[mf], f1, acc[mf][1], 0, 0, 0);
      }
    }

    #pragma unroll
    for (int mf = 0; mf < 4; ++mf)
      #pragma unroll
      for (int nf = 0; nf < 2; ++nf)
        #pragma unroll
        for (int v = 0; v < 4; ++v) {
          int mrow = w * 64 + mf * 16 + r * 4 + v;
          if (ch * 256 + mrow < nrows) {
            int col = n0 + nf * 16 + c;
            size_t ti = ((size_t)ch * nktH + (col >> 5)) * 8192 +
                        ((((col >> 3) & 3) * 256 + mrow) * 8) + (col & 7);
            float a = acc[mf][nf][v];
            if (FUSE) {
              float g = b2f(Gt[ti]);
              float s = g / (1.f + __expf(-g));
              Ht[ti] = f2b(s * a);
            } else {
              Gt[ti] = f2b(a);
            }
          }
        }
  }
}

template<int NKT>
__device__ __forceinline__ void dn_body(
    const unsigned short* __restrict__ Abase,   // h tile-linear, chunk stride NKT*8192
    const float* __restrict__ B,                // [K][D_HID]
    const int* __restrict__ tokp, const float* __restrict__ wtsp, float scale,
    int rowoff,                                  // global row offset when tokp==null
    float* __restrict__ out,
    int nch, int nrows, int n0)
{
  const int tid = threadIdx.x;
  const int w = tid >> 6, lane = tid & 63;
  const int c = lane & 15, r = lane >> 4;
  const float* bp0 = B + (size_t)(r * 8) * D_HID + n0 + c;
  const float* bp1 = bp0 + 16;

  for (int ch = 0; ch < nch; ++ch) {
    const unsigned short* Ach = Abase + (size_t)ch * NKT * 8192;
    floatx4 acc[4][2] = {};

    #pragma unroll 1
    for (int kt = 0; kt < NKT; ++kt) {
      float b0[8], b1[8];
      #pragma unroll
      for (int j = 0; j < 8; ++j) b0[j] = bp0[(size_t)(kt * 32 + j) * D_HID];
      #pragma unroll
      for (int j = 0; j < 8; ++j) b1[j] = bp1[(size_t)(kt * 32 + j) * D_HID];
      short8 af[4];
      #pragma unroll
      for (int mf = 0; mf < 4; ++mf)
        af[mf] = *(const short8*)(Ach + ((size_t)kt * 1024 + r * 256 + w * 64 + mf * 16 + c) * 8);
      short8 f0 = pack8s(b0), f1 = pack8s(b1);
      #pragma unroll
      for (int mf = 0; mf < 4; ++mf) {
        acc[mf][0] = __builtin_amdgcn_mfma_f32_16x16x32_bf16(af[mf], f0, acc[mf][0], 0, 0, 0);
        acc[mf][1] = __builtin_amdgcn_mfma_f32_16x16x32_bf16(af[mf], f1, acc[mf][1], 0, 0, 0);
      }
    }

    #pragma unroll
    for (int mf = 0; mf < 4; ++mf)
      #pragma unroll
      for (int nf = 0; nf < 2; ++nf)
        #pragma unroll
        for (int v = 0; v < 4; ++v) {
          int mrow = w * 64 + mf * 16 + r * 4 + v;
          int grow = ch * 256 + mrow;
          if (grow < nrows) {
            int tk = tokp ? tokp[grow] : (rowoff + grow);
            float wgt = wtsp ? wtsp[grow] * scale : scale;
            atomicAdd(&out[(size_t)tk * D_HID + n0 + nf * 16 + c],
                      wgt * acc[mf][nf][v]);
          }
        }
  }
}

// gate/up grid: 352 shared blocks first (4 ch x 88 n-tiles), then 32x44 routed.
__global__ __launch_bounds__(256, 4) void k_gate(
    const unsigned short* __restrict__ Ap, const unsigned short* __restrict__ ApS,
    const float* __restrict__ wg, const float* __restrict__ wsg,
    const int* __restrict__ cnt, const int* __restrict__ poff,
    unsigned short* __restrict__ gtR, unsigned short* __restrict__ gtS)
{
  int bid = blockIdx.x;
  if (bid < 352) {
    int ch = bid / 88, x = bid % 88;
    gu_body<64, SHI, false>(ApS + (size_t)ch * 64 * 8192, wsg,
                            gtS + (size_t)ch * 88 * 8192, nullptr, 88, 1, 256, x * 32);
  } else {
    int rel = bid - 352;
    int e = rel / 44, x = rel % 44;
    int nr = cnt[e];
    if (nr <= 0) return;
    size_t cb = (size_t)(poff[e] >> 8);
    gu_body<64, I_EXP, false>(Ap + cb * 64 * 8192, wg + (size_t)e * D_HID * I_EXP,
                              gtR + cb * 44 * 8192, nullptr, 44,
                              (nr + 255) >> 8, nr, x * 32);
  }
}

__global__ __launch_bounds__(256, 4) void k_up(
    const unsigned short* __restrict__ Ap, const unsigned short* __restrict__ ApS,
    const float* __restrict__ wu, const float* __restrict__ wsu,
    const int* __restrict__ cnt, const int* __restrict__ poff,
    unsigned short* __restrict__ gtR, unsigned short* __restrict__ gtS,
    unsigned short* __restrict__ htR, unsigned short* __restrict__ htS)
{
  int bid = blockIdx.x;
  if (bid < 352) {
    int ch = bid / 88, x = bid % 88;
    gu_body<64, SHI, true>(ApS + (size_t)ch * 64 * 8192, wsu,
                           gtS + (size_t)ch * 88 * 8192, htS + (size_t)ch * 88 * 8192,
                           88, 1, 256, x * 32);
  } else {
    int rel = bid - 352;
    int e = rel / 44, x = rel % 44;
    int nr = cnt[e];
    if (nr <= 0) return;
    size_t cb = (size_t)(poff[e] >> 8);
    gu_body<64, I_EXP, true>(Ap + cb * 64 * 8192, wu + (size_t)e * D_HID * I_EXP,
                             gtR + cb * 44 * 8192, htR + cb * 44 * 8192, 44,
                             (nr + 255) >> 8, nr, x * 32);
  }
}

// down grid: 256 shared blocks first (4 ch x 64 n-tiles), then 32x64 routed.
__global__ __launch_bounds__(256, 4) void k_down(
    const unsigned short* __restrict__ htR, const unsigned short* __restrict__ htS,
    const float* __restrict__ wd, const float* __restrict__ wsd,
    const int* __restrict__ offp, const int* __restrict__ cnt,
    const int* __restrict__ poff,
    const int* __restrict__ tok, const float* __restrict__ wts,
    float* __restrict__ out)
{
  int bid = blockIdx.x;
  if (bid < 256) {
    int ch = bid >> 6, x = bid & 63;
    dn_body<88>(htS + (size_t)ch * 88 * 8192, wsd, nullptr, nullptr, 1.0f,
                ch * 256, out, 1, 256, x * 32);
  } else {
    int rel = bid - 256;
    int e = rel >> 6, x = rel & 63;
    int nr = cnt[e];
    if (nr <= 0) return;
    size_t cb = (size_t)(poff[e] >> 8);
    dn_body<44>(htR + cb * 44 * 8192, wd + (size_t)e * I_EXP * D_HID,
                tok + offp[e], wts + offp[e], RSCALE, 0, out,
                (nr + 255) >> 8, nr, x * 32);
  }
}

extern "C" void kernel_launch(void* const* d_in, const int* in_sizes, int n_in,
                              void* d_out, int out_size, void* d_ws, size_t ws_size,
                              hipStream_t stream) {
  const float* x    = (const float*)d_in[0];
  const float* gw   = (const float*)d_in[1];
  const float* bias = (const float*)d_in[2];
  const float* wg   = (const float*)d_in[3];
  const float* wu   = (const float*)d_in[4];
  const float* wd   = (const float*)d_in[5];
  const float* wsg  = (const float*)d_in[6];
  const float* wsu  = (const float*)d_in[7];
  const float* wsd  = (const float*)d_in[8];
  float* out = (float*)d_out;

  char* ws = (char*)d_ws;
  size_t o = 0;
  auto take = [&](size_t bytes) {
    char* p = ws + o;
    o += (bytes + 255) & ~(size_t)255;
    return p;
  };
  int*   tki  = (int*)  take((size_t)T_TOK * TOPK * 4);
  float* tkw  = (float*)take((size_t)T_TOK * TOPK * 4);
  int*   cnt  = (int*)  take(NEXP * 4);
  int*   offp = (int*)  take((NEXP + 1) * 4);
  int*   poff = (int*)  take((NEXP + 1) * 4);
  int*   tok  = (int*)  take((size_t)T_TOK * TOPK * 4);
  float* wts  = (float*)take((size_t)T_TOK * TOPK * 4);
  // padded rows <= 6144 + 32*255 -> 14336 (56 chunks)
  unsigned short* Ap  = (unsigned short*)take((size_t)56 * 64 * 8192 * 2);
  unsigned short* ApS = (unsigned short*)take((size_t)4 * 64 * 8192 * 2);
  unsigned short* gtR = (unsigned short*)take((size_t)56 * 44 * 8192 * 2);
  unsigned short* gtS = (unsigned short*)take((size_t)4 * 88 * 8192 * 2);
  unsigned short* htR = (unsigned short*)take((size_t)56 * 44 * 8192 * 2);
  unsigned short* htS = (unsigned short*)take((size_t)4 * 88 * 8192 * 2);

  (void)hipMemsetAsync(out, 0, (size_t)T_TOK * D_HID * sizeof(float), stream);
  k_route<<<T_TOK, 64, 0, stream>>>(x, gw, bias, tki, tkw);
  k_count<<<1, 256, 0, stream>>>(tki, cnt, offp, poff);
  k_compact<<<NEXP, 64, 0, stream>>>(tki, tkw, offp, tok, wts);
  k_prep<<<dim3(NEXP + 1, 4), 256, 0, stream>>>(x, offp, cnt, poff, tok, Ap, ApS);

  k_gate<<<352 + 44 * NEXP, 256, 0, stream>>>(Ap, ApS, wg, wsg, cnt, poff, gtR, gtS);
  k_up<<<352 + 44 * NEXP, 256, 0, stream>>>(Ap, ApS, wu, wsu, cnt, poff, gtR, gtS, htR, htS);
  k_down<<<256 + 64 * NEXP, 256, 0, stream>>>(htR, htS, wd, wsd, offp, cnt, poff, tok, wts, out);
}